// Round 5
// baseline (863.774 us; speedup 1.0000x reference)
//
#include <hip/hip_runtime.h>

#define N_NODES 100000
#define N_EDGES 1600000
#define D_FEAT 64

#define N_PART 8
#define SLICE  (N_EDGES / N_PART)          // 200000, exact

#define RB_LOG 7
#define ROWS_PER_BUCKET 128                // rowoff fits in 7 bits
#define N_BUCKET ((N_NODES + ROWS_PER_BUCKET - 1) / ROWS_PER_BUCKET)  // 782
#define N_CELL (N_BUCKET * N_PART)         // 6256

#define COL_BITS 17
#define COL_MASK ((1 << COL_BITS) - 1)

// ---------------- phase A: 2D histogram count[part][bucket] ----------------
// 512 blocks; part = blockIdx&7 owns edge slice [part*SLICE, (part+1)*SLICE).
__global__ __launch_bounds__(256) void hist_kernel(
    const int* __restrict__ rows, int* __restrict__ histG)
{
    __shared__ int h[N_BUCKET];
    for (int i = threadIdx.x; i < N_BUCKET; i += 256) h[i] = 0;
    __syncthreads();

    int part = blockIdx.x & (N_PART - 1);
    int blk  = blockIdx.x >> 3;
    int nblk = gridDim.x >> 3;
    int base = part * SLICE;

    for (int e = blk * 256 + threadIdx.x; e < SLICE; e += nblk * 256)
        atomicAdd(&h[rows[base + e] >> RB_LOG], 1);
    __syncthreads();

    // merge into part-local region histG[part*N_BUCKET + b]
    for (int i = threadIdx.x; i < N_BUCKET; i += 256)
        if (h[i]) atomicAdd(&histG[part * N_BUCKET + i], h[i]);
}

// ---------------- phase B: scan 6256 cells in bucket-major order -----------
// cell cm = b*8 + p reads histG[p*N_BUCKET + b]; writes exclusive prefix to
// cellptr[cm] and cursor[p*N_BUCKET + b]. Single block of 1024 threads.
__global__ __launch_bounds__(1024) void scan_kernel(
    const int* __restrict__ histG, int* __restrict__ cellptr,
    int* __restrict__ cursor)
{
    const int PER = 8;  // 1024*8 = 8192 >= 6256
    __shared__ int buf[2][1024];
    int t = threadIdx.x;

    int v[PER], pre[PER];
    int s = 0;
    #pragma unroll
    for (int j = 0; j < PER; ++j) {
        int cm = t * PER + j;
        int x = 0;
        if (cm < N_CELL) x = histG[(cm & (N_PART - 1)) * N_BUCKET + (cm >> 3)];
        pre[j] = s; v[j] = x; s += x;
    }
    buf[0][t] = s;
    __syncthreads();
    int src = 0;
    for (int off = 1; off < 1024; off <<= 1) {
        int dst = 1 - src;
        int x = buf[src][t];
        if (t >= off) x += buf[src][t - off];
        buf[dst][t] = x;
        __syncthreads();
        src = dst;
    }
    int offset = buf[src][t] - s;  // exclusive across threads
    #pragma unroll
    for (int j = 0; j < PER; ++j) {
        int cm = t * PER + j;
        if (cm < N_CELL) {
            int val = offset + pre[j];
            cellptr[cm] = val;
            cursor[(cm & (N_PART - 1)) * N_BUCKET + (cm >> 3)] = val;
        }
    }
    if (t == 0) cellptr[N_CELL] = N_EDGES;
    (void)v;
}

// ---------------- phase C: append edges into (part,bucket) cells -----------
// Active write frontier = N_BUCKET open lines per part (~50 KB) -> lines fill
// quickly and are written to HBM once.
__global__ __launch_bounds__(256) void scatter_kernel(
    const float* __restrict__ vals, const int* __restrict__ rows,
    const int* __restrict__ cols, int* __restrict__ cursor,
    int2* __restrict__ rec)
{
    int part = blockIdx.x & (N_PART - 1);
    int blk  = blockIdx.x >> 3;
    int nblk = gridDim.x >> 3;
    int base = part * SLICE;
    int* cur = cursor + part * N_BUCKET;

    for (int e = blk * 256 + threadIdx.x; e < SLICE; e += nblk * 256) {
        int idx = base + e;
        int r = rows[idx];
        int b = r >> RB_LOG;
        int pos = atomicAdd(&cur[b], 1);
        int packed = ((r & (ROWS_PER_BUCKET - 1)) << COL_BITS) | cols[idx];
        rec[pos] = make_int2(packed, __float_as_int(vals[idx]));
    }
}

// ---------------- phase D: per-bucket gather + LDS accumulate --------------
// One block per bucket. LDS accum 128 rows x 64 f32 = 32 KB, bank-swizzled.
__global__ __launch_bounds__(256) void gather_kernel(
    const float* __restrict__ H, const int2* __restrict__ rec,
    const int* __restrict__ cellptr, float* __restrict__ out)
{
    __shared__ float acc[ROWS_PER_BUCKET * D_FEAT];  // 32 KB
    for (int i = threadIdx.x; i < ROWS_PER_BUCKET * D_FEAT; i += 256)
        acc[i] = 0.f;
    __syncthreads();

    int b = blockIdx.x;
    int start = cellptr[b * N_PART];
    int end   = cellptr[b * N_PART + N_PART];

    int g  = threadIdx.x >> 4;   // record group 0..15
    int fc = threadIdx.x & 15;   // feature chunk
    const float4* H4 = reinterpret_cast<const float4*>(H);

    int i = start + g;
    // 2-way unrolled: records i and i+16 per group per iteration
    for (; i + 16 < end; i += 32) {
        int2 r0 = rec[i];
        int2 r1 = rec[i + 16];
        int c0 = r0.x & COL_MASK, ro0 = r0.x >> COL_BITS;
        int c1 = r1.x & COL_MASK, ro1 = r1.x >> COL_BITS;
        float4 h0 = H4[c0 * 16 + fc];
        float4 h1 = H4[c1 * 16 + fc];
        float v0 = __int_as_float(r0.y);
        float v1 = __int_as_float(r1.y);
        int f0 = (fc + ro0) & 15;   // bank swizzle
        int f1 = (fc + ro1) & 15;
        float* a0 = &acc[ro0 * D_FEAT + f0 * 4];
        float* a1 = &acc[ro1 * D_FEAT + f1 * 4];
        atomicAdd(a0 + 0, v0 * h0.x); atomicAdd(a0 + 1, v0 * h0.y);
        atomicAdd(a0 + 2, v0 * h0.z); atomicAdd(a0 + 3, v0 * h0.w);
        atomicAdd(a1 + 0, v1 * h1.x); atomicAdd(a1 + 1, v1 * h1.y);
        atomicAdd(a1 + 2, v1 * h1.z); atomicAdd(a1 + 3, v1 * h1.w);
    }
    if (i < end) {
        int2 r0 = rec[i];
        int c0 = r0.x & COL_MASK, ro0 = r0.x >> COL_BITS;
        float4 h0 = H4[c0 * 16 + fc];
        float v0 = __int_as_float(r0.y);
        int f0 = (fc + ro0) & 15;
        float* a0 = &acc[ro0 * D_FEAT + f0 * 4];
        atomicAdd(a0 + 0, v0 * h0.x); atomicAdd(a0 + 1, v0 * h0.y);
        atomicAdd(a0 + 2, v0 * h0.z); atomicAdd(a0 + 3, v0 * h0.w);
    }
    __syncthreads();

    // writeback: un-swizzle, coalesced float4 stores, exactly once
    int rowbase = b * ROWS_PER_BUCKET;
    for (int ro = threadIdx.x >> 4; ro < ROWS_PER_BUCKET; ro += 16) {
        int row = rowbase + ro;
        if (row < N_NODES) {
            int fp = (fc + ro) & 15;
            float4 r4 = *reinterpret_cast<float4*>(&acc[ro * D_FEAT + fp * 4]);
            reinterpret_cast<float4*>(out)[row * 16 + fc] = r4;
        }
    }
}

extern "C" void kernel_launch(void* const* d_in, const int* in_sizes, int n_in,
                              void* d_out, int out_size, void* d_ws, size_t ws_size,
                              hipStream_t stream) {
    const float* H    = (const float*)d_in[0];
    const float* vals = (const float*)d_in[1];
    const int*   rows = (const int*)d_in[2];
    const int*   cols = (const int*)d_in[3];
    float* out = (float*)d_out;

    char* ws = (char*)d_ws;
    int2* rec     = (int2*)ws;                       // E * 8B = 12.8 MB
    int*  histG   = (int*)(rec + N_EDGES);           // N_PART*N_BUCKET
    int*  cursor  = histG + N_PART * N_BUCKET;       // N_PART*N_BUCKET
    int*  cellptr = cursor + N_PART * N_BUCKET;      // N_CELL+1

    hipMemsetAsync(histG, 0, N_PART * N_BUCKET * sizeof(int), stream);

    hist_kernel<<<512, 256, 0, stream>>>(rows, histG);
    scan_kernel<<<1, 1024, 0, stream>>>(histG, cellptr, cursor);
    scatter_kernel<<<512, 256, 0, stream>>>(vals, rows, cols, cursor, rec);
    gather_kernel<<<N_BUCKET, 256, 0, stream>>>(H, rec, cellptr, out);
}

// Round 6
// 252.384 us; speedup vs baseline: 3.4225x; 3.4225x over previous
//
#include <hip/hip_runtime.h>

#define N_NODES 100000
#define N_EDGES 1600000
#define D_FEAT 64

#define N_PART 8
#define SLICE  (N_EDGES / N_PART)          // 200000, exact

#define RB_LOG 7
#define ROWS_PER_BUCKET 128                // rowoff fits in 7 bits
#define N_BUCKET ((N_NODES + ROWS_PER_BUCKET - 1) / ROWS_PER_BUCKET)  // 782
#define N_CELL (N_BUCKET * N_PART)         // 6256

#define COL_BITS 17
#define COL_MASK ((1 << COL_BITS) - 1)

#define MAXREC 3072   // per-bucket chunk size; bucket mean 2048, sigma~45

// ---------------- phase A: 2D histogram count[part][bucket] ----------------
__global__ __launch_bounds__(256) void hist_kernel(
    const int* __restrict__ rows, int* __restrict__ histG)
{
    __shared__ int h[N_BUCKET];
    for (int i = threadIdx.x; i < N_BUCKET; i += 256) h[i] = 0;
    __syncthreads();

    int part = blockIdx.x & (N_PART - 1);
    int blk  = blockIdx.x >> 3;
    int nblk = gridDim.x >> 3;
    int base = part * SLICE;

    for (int e = blk * 256 + threadIdx.x; e < SLICE; e += nblk * 256)
        atomicAdd(&h[rows[base + e] >> RB_LOG], 1);
    __syncthreads();

    for (int i = threadIdx.x; i < N_BUCKET; i += 256)
        if (h[i]) atomicAdd(&histG[part * N_BUCKET + i], h[i]);
}

// ---------------- phase B: scan 6256 cells in bucket-major order -----------
__global__ __launch_bounds__(1024) void scan_kernel(
    const int* __restrict__ histG, int* __restrict__ cellptr,
    int* __restrict__ cursor)
{
    const int PER = 8;
    __shared__ int buf[2][1024];
    int t = threadIdx.x;

    int pre[PER];
    int s = 0;
    #pragma unroll
    for (int j = 0; j < PER; ++j) {
        int cm = t * PER + j;
        int x = 0;
        if (cm < N_CELL) x = histG[(cm & (N_PART - 1)) * N_BUCKET + (cm >> 3)];
        pre[j] = s; s += x;
    }
    buf[0][t] = s;
    __syncthreads();
    int src = 0;
    for (int off = 1; off < 1024; off <<= 1) {
        int dst = 1 - src;
        int x = buf[src][t];
        if (t >= off) x += buf[src][t - off];
        buf[dst][t] = x;
        __syncthreads();
        src = dst;
    }
    int offset = buf[src][t] - s;
    #pragma unroll
    for (int j = 0; j < PER; ++j) {
        int cm = t * PER + j;
        if (cm < N_CELL) {
            int val = offset + pre[j];
            cellptr[cm] = val;
            cursor[(cm & (N_PART - 1)) * N_BUCKET + (cm >> 3)] = val;
        }
    }
    if (t == 0) cellptr[N_CELL] = N_EDGES;
}

// ---------------- phase C: append edges into (part,bucket) cells -----------
__global__ __launch_bounds__(256) void scatter_kernel(
    const float* __restrict__ vals, const int* __restrict__ rows,
    const int* __restrict__ cols, int* __restrict__ cursor,
    int2* __restrict__ rec)
{
    int part = blockIdx.x & (N_PART - 1);
    int blk  = blockIdx.x >> 3;
    int nblk = gridDim.x >> 3;
    int base = part * SLICE;
    int* cur = cursor + part * N_BUCKET;

    for (int e = blk * 256 + threadIdx.x; e < SLICE; e += nblk * 256) {
        int idx = base + e;
        int r = rows[idx];
        int b = r >> RB_LOG;
        int pos = atomicAdd(&cur[b], 1);
        int packed = ((r & (ROWS_PER_BUCKET - 1)) << COL_BITS) | cols[idx];
        rec[pos] = make_int2(packed, __float_as_int(vals[idx]));
    }
}

// ---------------- phase D: per-bucket LDS index-sort + register gather ------
// One block per bucket. Sort record INDICES by row in LDS, then each
// (row, feature-chunk) task accumulates its float4 in REGISTERS.
__global__ __launch_bounds__(256) void gather_kernel(
    const float* __restrict__ H, const int2* __restrict__ rec,
    const int* __restrict__ cellptr, float* __restrict__ out)
{
    __shared__ int2           recbuf[MAXREC];               // 24 KB
    __shared__ unsigned short order[MAXREC];                // 6 KB
    __shared__ int            rstart[ROWS_PER_BUCKET + 1];
    __shared__ int            rcur[ROWS_PER_BUCKET];
    __shared__ int            sbuf[2][ROWS_PER_BUCKET];     // scan scratch

    int b = blockIdx.x;
    int start = cellptr[b * N_PART];
    int end   = cellptr[b * N_PART + N_PART];

    int tid = threadIdx.x;
    int rg = tid >> 4;       // row group 0..15
    int fc = tid & 15;       // feature chunk 0..15
    const float4* H4 = reinterpret_cast<const float4*>(H);

    float4 acc[8];
    #pragma unroll
    for (int k = 0; k < 8; ++k) acc[k] = make_float4(0.f, 0.f, 0.f, 0.f);

    for (int base = start; base < end; base += MAXREC) {
        int n = min(end - base, MAXREC);

        if (tid < ROWS_PER_BUCKET) rcur[tid] = 0;   // rcur = histogram
        __syncthreads();

        // load records + histogram rows
        for (int i = tid; i < n; i += 256) {
            int2 r = rec[base + i];
            recbuf[i] = r;
            atomicAdd(&rcur[r.x >> COL_BITS], 1);
        }
        __syncthreads();

        // inclusive scan of 128 counts -> rstart (exclusive boundaries)
        if (tid < ROWS_PER_BUCKET) sbuf[0][tid] = rcur[tid];
        __syncthreads();
        int src = 0;
        for (int off = 1; off < ROWS_PER_BUCKET; off <<= 1) {
            if (tid < ROWS_PER_BUCKET) {
                int x = sbuf[src][tid];
                if (tid >= off) x += sbuf[src][tid - off];
                sbuf[1 - src][tid] = x;
            }
            __syncthreads();
            src ^= 1;
        }
        if (tid < ROWS_PER_BUCKET) rstart[tid + 1] = sbuf[src][tid];
        if (tid == 0) rstart[0] = 0;
        __syncthreads();
        if (tid < ROWS_PER_BUCKET) rcur[tid] = rstart[tid];  // scatter cursors
        __syncthreads();

        // index-sort: order[pos] = record index, grouped by row
        for (int i = tid; i < n; i += 256) {
            int ro = recbuf[i].x >> COL_BITS;
            int pos = atomicAdd(&rcur[ro], 1);
            order[pos] = (unsigned short)i;
        }
        __syncthreads();

        // register-accumulate gather: 16 lanes x float4 per row
        #pragma unroll
        for (int k = 0; k < 8; ++k) {
            int ro = k * 16 + rg;
            int s = rstart[ro], e2 = rstart[ro + 1];
            int i = s;
            for (; i + 2 <= e2; i += 2) {
                int j0 = order[i], j1 = order[i + 1];
                int2 r0 = recbuf[j0];
                int2 r1 = recbuf[j1];
                float4 h0 = H4[(r0.x & COL_MASK) * 16 + fc];
                float4 h1 = H4[(r1.x & COL_MASK) * 16 + fc];
                float v0 = __int_as_float(r0.y);
                float v1 = __int_as_float(r1.y);
                acc[k].x += v0 * h0.x; acc[k].y += v0 * h0.y;
                acc[k].z += v0 * h0.z; acc[k].w += v0 * h0.w;
                acc[k].x += v1 * h1.x; acc[k].y += v1 * h1.y;
                acc[k].z += v1 * h1.z; acc[k].w += v1 * h1.w;
            }
            if (i < e2) {
                int j0 = order[i];
                int2 r0 = recbuf[j0];
                float4 h0 = H4[(r0.x & COL_MASK) * 16 + fc];
                float v0 = __int_as_float(r0.y);
                acc[k].x += v0 * h0.x; acc[k].y += v0 * h0.y;
                acc[k].z += v0 * h0.z; acc[k].w += v0 * h0.w;
            }
        }
        __syncthreads();   // LDS reused next chunk
    }

    // coalesced writeback, exactly once
    int rowbase = b * ROWS_PER_BUCKET;
    #pragma unroll
    for (int k = 0; k < 8; ++k) {
        int row = rowbase + k * 16 + rg;
        if (row < N_NODES)
            reinterpret_cast<float4*>(out)[row * 16 + fc] = acc[k];
    }
}

extern "C" void kernel_launch(void* const* d_in, const int* in_sizes, int n_in,
                              void* d_out, int out_size, void* d_ws, size_t ws_size,
                              hipStream_t stream) {
    const float* H    = (const float*)d_in[0];
    const float* vals = (const float*)d_in[1];
    const int*   rows = (const int*)d_in[2];
    const int*   cols = (const int*)d_in[3];
    float* out = (float*)d_out;

    char* ws = (char*)d_ws;
    int2* rec     = (int2*)ws;                       // E * 8B = 12.8 MB
    int*  histG   = (int*)(rec + N_EDGES);           // N_PART*N_BUCKET
    int*  cursor  = histG + N_PART * N_BUCKET;       // N_PART*N_BUCKET
    int*  cellptr = cursor + N_PART * N_BUCKET;      // N_CELL+1

    hipMemsetAsync(histG, 0, N_PART * N_BUCKET * sizeof(int), stream);

    hist_kernel<<<512, 256, 0, stream>>>(rows, histG);
    scan_kernel<<<1, 1024, 0, stream>>>(histG, cellptr, cursor);
    scatter_kernel<<<512, 256, 0, stream>>>(vals, rows, cols, cursor, rec);
    gather_kernel<<<N_BUCKET, 256, 0, stream>>>(H, rec, cellptr, out);
}